// Round 2
// baseline (465.193 us; speedup 1.0000x reference)
//
#include <hip/hip_runtime.h>
#include <math.h>

// Problem constants: B=512, S=4096, H=32, D=16
#define BB   512
#define SS   4096
#define HH   32
#define DD   16
#define NT   1024            // one block per batch row, 16 waves
#define RPT  (SS / NT)       // 4 rows per thread
#define EPSI 1e-8f

__global__ __launch_bounds__(NT, 4)   // cap at 128 VGPR -> 16 waves/CU
void attn_cos_logsoftmax(const float* __restrict__ dec,   // [B,H]
                         const float* __restrict__ enc,   // [B,S,H]
                         const float* __restrict__ Wq,    // [D,H]
                         const float* __restrict__ bq,    // [D]
                         const float* __restrict__ Wk,    // [D,H]
                         const float* __restrict__ bk,    // [D]
                         float* __restrict__ out)         // [B,1,S]
{
    __shared__ float knS[DD];     // normalized k projection (block-uniform)
    __shared__ float red1[16];    // cross-wave max scratch
    __shared__ float red2[16];    // cross-wave sum scratch

    const int t = threadIdx.x;
    const int b = blockIdx.x;

    const float* encb = enc + (size_t)b * SS * HH;

    // ---- Issue row-0 global loads FIRST so they overlap the kn phase ----
    // hbuf as plain float arrays with constant indices -> fully register-promoted.
    float hbuf[2][HH];
    {
        const float4* p = (const float4*)(encb + (size_t)t * HH);  // row r = t (c=0)
#pragma unroll
        for (int i = 0; i < 8; ++i) {
            float4 v = p[i];
            hbuf[0][i * 4 + 0] = v.x;
            hbuf[0][i * 4 + 1] = v.y;
            hbuf[0][i * 4 + 2] = v.z;
            hbuf[0][i * 4 + 3] = v.w;
        }
    }

    // ---- kn = normalize(dec[b] @ Wk^T + bk): block-uniform, computed
    // redundantly (all operands wave-uniform -> s_loads), stored to LDS ----
    {
        float dh[HH];
#pragma unroll
        for (int h = 0; h < HH; ++h) dh[h] = dec[b * HH + h];
        float kacc[DD];
        float ssk = 0.f;
#pragma unroll
        for (int d = 0; d < DD; ++d) {
            float a = bk[d];
#pragma unroll
            for (int h = 0; h < HH; ++h) a = fmaf(Wk[d * HH + h], dh[h], a);
            kacc[d] = a;
            ssk = fmaf(a, a, ssk);
        }
        float inv = 1.f / fmaxf(sqrtf(ssk), EPSI);
        if (t == 0) {
#pragma unroll
            for (int d = 0; d < DD; ++d) knS[d] = kacc[d] * inv;
        }
    }
    __syncthreads();   // knS visible before first epilogue read

    float att[RPT];

#pragma unroll
    for (int c = 0; c < RPT; ++c) {
        const int cur = c & 1;
        const int nxt = cur ^ 1;

        // Prefetch next row's 32 floats into the other buffer; the s_waitcnt
        // for these lands at the NEXT iteration's first use, so they stay in
        // flight under this iteration's 512-FMA phase.
        if (c + 1 < RPT) {
            const float4* p =
                (const float4*)(encb + (size_t)((c + 1) * NT + t) * HH);
#pragma unroll
            for (int i = 0; i < 8; ++i) {
                float4 v = p[i];
                hbuf[nxt][i * 4 + 0] = v.x;
                hbuf[nxt][i * 4 + 1] = v.y;
                hbuf[nxt][i * 4 + 2] = v.z;
                hbuf[nxt][i * 4 + 3] = v.w;
            }
        }

        // q = Wq @ h + bq. Wq/bq indices are unroll constants -> wave-uniform
        // -> s_load; FMAs take the weight as an SGPR operand (no LDS, no VGPR).
        float q[DD];
#pragma unroll
        for (int d = 0; d < DD; ++d) q[d] = bq[d];
#pragma unroll
        for (int h = 0; h < HH; ++h) {
            float hv = hbuf[cur][h];
#pragma unroll
            for (int d = 0; d < DD; ++d)
                q[d] = fmaf(Wq[d * HH + h], hv, q[d]);
        }

        // cosine vs kn: kn read from LDS in float4 windows (broadcast b128)
        float ss = 0.f, num = 0.f;
#pragma unroll
        for (int dd = 0; dd < DD; dd += 4) {
            float4 k4 = *((const float4*)&knS[dd]);
            ss  = fmaf(q[dd + 0], q[dd + 0], ss);
            ss  = fmaf(q[dd + 1], q[dd + 1], ss);
            ss  = fmaf(q[dd + 2], q[dd + 2], ss);
            ss  = fmaf(q[dd + 3], q[dd + 3], ss);
            num = fmaf(q[dd + 0], k4.x, num);
            num = fmaf(q[dd + 1], k4.y, num);
            num = fmaf(q[dd + 2], k4.z, num);
            num = fmaf(q[dd + 3], k4.w, num);
        }
        att[c] = num / fmaxf(sqrtf(ss), EPSI);
    }

    // ---- block log-softmax over 4096 values (16 waves) ----
    const int wave = t >> 6;

    float m = att[0];
#pragma unroll
    for (int c = 1; c < RPT; ++c) m = fmaxf(m, att[c]);
#pragma unroll
    for (int off = 32; off >= 1; off >>= 1) m = fmaxf(m, __shfl_down(m, off));
    if ((t & 63) == 0) red1[wave] = m;
    __syncthreads();
    float M = red1[0];
#pragma unroll
    for (int w = 1; w < 16; ++w) M = fmaxf(M, red1[w]);

    float s = 0.f;
#pragma unroll
    for (int c = 0; c < RPT; ++c) s += __expf(att[c] - M);
#pragma unroll
    for (int off = 32; off >= 1; off >>= 1) s += __shfl_down(s, off);
    if ((t & 63) == 0) red2[wave] = s;
    __syncthreads();
    float S = 0.f;
#pragma unroll
    for (int w = 0; w < 16; ++w) S += red2[w];

    const float logZ = M + __logf(S);

    float* ob = out + (size_t)b * SS;
#pragma unroll
    for (int c = 0; c < RPT; ++c) ob[c * NT + t] = att[c] - logZ;
}

extern "C" void kernel_launch(void* const* d_in, const int* in_sizes, int n_in,
                              void* d_out, int out_size, void* d_ws, size_t ws_size,
                              hipStream_t stream) {
    const float* dec = (const float*)d_in[0];  // [512,32]
    const float* enc = (const float*)d_in[1];  // [512,4096,32]
    const float* Wq  = (const float*)d_in[2];  // [16,32]
    const float* bq  = (const float*)d_in[3];  // [16]
    const float* Wk  = (const float*)d_in[4];  // [16,32]
    const float* bk  = (const float*)d_in[5];  // [16]
    float* out = (float*)d_out;                // [512,1,4096]

    attn_cos_logsoftmax<<<dim3(BB), dim3(NT), 0, stream>>>(dec, enc, Wq, bq, Wk, bk, out);
}

// Round 3
// 379.526 us; speedup vs baseline: 1.2257x; 1.2257x over previous
//
#include <hip/hip_runtime.h>
#include <math.h>

// Problem: B=512, S=4096, H=32, D=16
// q = enc @ WqT + bq  ->  one mfma_f32_16x16x32_bf16 per 16 rows (K=32=H).
#define BB    512
#define SS    4096
#define HH    32
#define DD    16
#define NT    256                 // 4 waves per block; one block per batch row
#define CHUNK 256                 // encoder rows per LDS chunk
#define NCH   (SS / CHUNK)        // 16 chunks
#define TILES (CHUNK / 16)        // 16 MFMA tiles per chunk
#define TPW   (TILES / 4)         // 4 tiles per wave
#define EPSI  1e-8f

typedef __attribute__((ext_vector_type(8))) short   short8;   // 8 bf16 = 4 VGPR
typedef __attribute__((ext_vector_type(4))) float   floatx4;  // MFMA acc

// fp32 -> bf16 with round-to-nearest-even
__device__ __forceinline__ short bf16_of(float f) {
    union { float f; unsigned u; } v; v.f = f;
    return (short)((v.u + 0x7FFFu + ((v.u >> 16) & 1u)) >> 16);
}

// DPP add stages (VALU-only cross-lane reduce within 16-lane rows)
template <int CTRL>
__device__ __forceinline__ float dpp_add(float x) {
    int xi = __builtin_bit_cast(int, x);
    int yi = __builtin_amdgcn_update_dpp(0, xi, CTRL, 0xF, 0xF, true);
    return x + __builtin_bit_cast(float, yi);
}
// full sum across the 16 lanes of a DPP row (all lanes end with the total)
__device__ __forceinline__ float red16(float x) {
    x = dpp_add<0xB1>(x);    // quad_perm [1,0,3,2] : ^1
    x = dpp_add<0x4E>(x);    // quad_perm [2,3,0,1] : ^2
    x = dpp_add<0x141>(x);   // row_half_mirror     : + other quad
    x = dpp_add<0x140>(x);   // row_mirror          : + other 8-half
    return x;
}

__global__ __launch_bounds__(NT, 2)
void attn_cos_logsoftmax(const float* __restrict__ dec,   // [B,H]
                         const float* __restrict__ enc,   // [B,S,H]
                         const float* __restrict__ Wq,    // [D,H]
                         const float* __restrict__ bq,    // [D]
                         const float* __restrict__ Wk,    // [D,H]
                         const float* __restrict__ bk,    // [D]
                         float* __restrict__ out)         // [B,1,S]
{
    __shared__ short encS[2][CHUNK * HH];  // bf16 chunk, row-major, double-buffered (2x16 KB)
    __shared__ float attS[SS];             // per-row attention logits (16 KB)
    __shared__ float knS[DD];
    __shared__ float redM[4], redS[4];

    const int t    = threadIdx.x;
    const int b    = blockIdx.x;
    const int lane = t & 63;
    const int wv   = t >> 6;        // wave id 0..3
    const int l15  = lane & 15;     // MFMA n / m index
    const int quad = lane >> 4;     // MFMA k-slice / row-quadrant

    const float4* encb4 = (const float4*)(enc + (size_t)b * SS * HH);

    // ---- prefetch chunk 0 (coalesced: lane-consecutive float4) ----
    float4 pf[8];
#pragma unroll
    for (int i = 0; i < 8; ++i) pf[i] = encb4[i * NT + t];

    // ---- B fragment: Wq as bf16, resident in 4 VGPRs.
    // B[k=h][n=d] layout: lane needs Wq[l15][quad*8 + j], j=0..7 (contiguous). ----
    short8 bfrag;
    {
        const float* wp = Wq + l15 * HH + quad * 8;
        float4 w0 = *(const float4*)wp;
        float4 w1 = *(const float4*)(wp + 4);
        bfrag[0] = bf16_of(w0.x); bfrag[1] = bf16_of(w0.y);
        bfrag[2] = bf16_of(w0.z); bfrag[3] = bf16_of(w0.w);
        bfrag[4] = bf16_of(w1.x); bfrag[5] = bf16_of(w1.y);
        bfrag[6] = bf16_of(w1.z); bfrag[7] = bf16_of(w1.w);
    }

    // qlin bias term per lane: bq[d = l15]
    const float bqV = bq[l15];

    // ---- kn = normalize(dec[b] @ Wk^T + bk): all operands uniform -> s_loads;
    // computed redundantly (overlaps the in-flight prefetch), t==0 stores. ----
    {
        float dh[HH];
#pragma unroll
        for (int h = 0; h < HH; ++h) dh[h] = dec[b * HH + h];
        float kacc[DD], ssk = 0.f;
#pragma unroll
        for (int d = 0; d < DD; ++d) {
            float a = bk[d];
#pragma unroll
            for (int h = 0; h < HH; ++h) a = fmaf(Wk[d * HH + h], dh[h], a);
            kacc[d] = a; ssk = fmaf(a, a, ssk);
        }
        float inv = 1.f / fmaxf(sqrtf(ssk), EPSI);
        if (t == 0) {
#pragma unroll
            for (int d = 0; d < DD; ++d) knS[d] = kacc[d] * inv;
        }
    }
    __syncthreads();
    const float knV = knS[l15];   // broadcast ds_read

    // ---- main loop: stage fp32->bf16 chunk, MFMA, DPP epilogue ----
    for (int c = 0; c < NCH; ++c) {
        short* dst = encS[c & 1];
        // drain prefetch regs -> bf16 LDS (lane-consecutive 8B: conflict-free)
#pragma unroll
        for (int i = 0; i < 8; ++i) {
            union { short s[4]; unsigned long long u; } pk;
            pk.s[0] = bf16_of(pf[i].x); pk.s[1] = bf16_of(pf[i].y);
            pk.s[2] = bf16_of(pf[i].z); pk.s[3] = bf16_of(pf[i].w);
            *(unsigned long long*)&dst[(i * NT + t) * 4] = pk.u;
        }
        // issue next chunk's global loads (stay in flight under compute)
        if (c + 1 < NCH) {
            const float4* src = encb4 + (size_t)(c + 1) * (CHUNK * HH / 4);
#pragma unroll
            for (int i = 0; i < 8; ++i) pf[i] = src[i * NT + t];
        }
        __syncthreads();   // single barrier/iter: dbuf makes the 2nd unnecessary

        const short* sbuf = encS[c & 1];
        const int cbase = c * CHUNK;
#pragma unroll
        for (int i2 = 0; i2 < TPW; ++i2) {
            const int tile = wv * TPW + i2;
            // A fragment: A[m=l15][k=quad*8+j] -> one ds_read_b128 per lane
            short8 afrag = *(const short8*)&sbuf[(tile * 16 + l15) * HH + quad * 8];
            floatx4 acc = {0.f, 0.f, 0.f, 0.f};
            acc = __builtin_amdgcn_mfma_f32_16x16x32_bf16(afrag, bfrag, acc, 0, 0, 0);
            // acc[r] = qlin[row = tile*16 + quad*4 + r][d = l15]; add bias, reduce over d
            float4 av;
            float* avp = &av.x;
#pragma unroll
            for (int r = 0; r < 4; ++r) {
                float qv = acc[r] + bqV;
                float ss = red16(qv * qv);
                float nu = red16(qv * knV);
                avp[r] = nu / fmaxf(sqrtf(ss), EPSI);
            }
            if (l15 == 0)   // 4 writer lanes/wave, contiguous 16B each
                *(float4*)&attS[cbase + tile * 16 + quad * 4] = av;
        }
    }
    __syncthreads();

    // ---- block log-softmax over attS[4096] ----
    float m = -INFINITY;
#pragma unroll
    for (int i = 0; i < 16; ++i) m = fmaxf(m, attS[t + i * NT]);
#pragma unroll
    for (int off = 32; off >= 1; off >>= 1) m = fmaxf(m, __shfl_down(m, off));
    if (lane == 0) redM[wv] = m;
    __syncthreads();
    const float M = fmaxf(fmaxf(redM[0], redM[1]), fmaxf(redM[2], redM[3]));

    float s = 0.f;
#pragma unroll
    for (int i = 0; i < 16; ++i) s += __expf(attS[t + i * NT] - M);
#pragma unroll
    for (int off = 32; off >= 1; off >>= 1) s += __shfl_down(s, off);
    if (lane == 0) redS[wv] = s;
    __syncthreads();
    const float S = (redS[0] + redS[1]) + (redS[2] + redS[3]);
    const float logZ = M + __logf(S);

    // coalesced float4 output
    float4* ob4 = (float4*)(out + (size_t)b * SS);
#pragma unroll
    for (int i = 0; i < 4; ++i) {
        float4 a4 = *(const float4*)&attS[(t + i * NT) * 4];
        a4.x -= logZ; a4.y -= logZ; a4.z -= logZ; a4.w -= logZ;
        ob4[t + i * NT] = a4;
    }
}

extern "C" void kernel_launch(void* const* d_in, const int* in_sizes, int n_in,
                              void* d_out, int out_size, void* d_ws, size_t ws_size,
                              hipStream_t stream) {
    const float* dec = (const float*)d_in[0];  // [512,32]
    const float* enc = (const float*)d_in[1];  // [512,4096,32]
    const float* Wq  = (const float*)d_in[2];  // [16,32]
    const float* bq  = (const float*)d_in[3];  // [16]
    const float* Wk  = (const float*)d_in[4];  // [16,32]
    const float* bk  = (const float*)d_in[5];  // [16]
    float* out = (float*)d_out;                // [512,1,4096]

    attn_cos_logsoftmax<<<dim3(BB), dim3(NT), 0, stream>>>(dec, enc, Wq, bq, Wk, bk, out);
}

// Round 4
// 376.201 us; speedup vs baseline: 1.2366x; 1.0088x over previous
//
#include <hip/hip_runtime.h>
#include <math.h>

// Problem: B=512, S=4096, H=32, D=16
// q = enc @ WqT + bq via one mfma_f32_16x16x32_bf16 per 16 rows (K=32=H).
// Barrier-free streaming: A-fragments built directly from coalesced global
// loads (no LDS staging), depth-4 register pipeline per wave.
#define BB    512
#define SS    4096
#define HH    32
#define DD    16
#define NT    256                          // 4 waves/block, one block per batch row
#define WAVES 4
#define RPW   (SS / WAVES)                 // 1024 rows per wave
#define TPW   (RPW / 16)                   // 64 MFMA tiles per wave
#define DEPTH 4                            // register pipeline depth (tiles)
#define NGRP  (TPW / DEPTH)                // 16 groups
#define EPSI  1e-8f

typedef __attribute__((ext_vector_type(8))) short   short8;   // 8 bf16 = 4 VGPR
typedef __attribute__((ext_vector_type(4))) float   floatx4;  // MFMA acc

// fp32 -> bf16 round-to-nearest-even
__device__ __forceinline__ short bf16_of(float f) {
    union { float f; unsigned u; } v; v.f = f;
    return (short)((v.u + 0x7FFFu + ((v.u >> 16) & 1u)) >> 16);
}

// VALU-only cross-lane add within each 16-lane DPP row
template <int CTRL>
__device__ __forceinline__ float dpp_add(float x) {
    int xi = __builtin_bit_cast(int, x);
    int yi = __builtin_amdgcn_update_dpp(0, xi, CTRL, 0xF, 0xF, true);
    return x + __builtin_bit_cast(float, yi);
}
__device__ __forceinline__ float red16(float x) {
    x = dpp_add<0xB1>(x);    // quad_perm ^1
    x = dpp_add<0x4E>(x);    // quad_perm ^2
    x = dpp_add<0x141>(x);   // row_half_mirror
    x = dpp_add<0x140>(x);   // row_mirror
    return x;                // all 16 lanes hold the row total
}

__global__ __launch_bounds__(NT, 2)
void attn_cos_logsoftmax(const float* __restrict__ dec,   // [B,H]
                         const float* __restrict__ enc,   // [B,S,H]
                         const float* __restrict__ Wq,    // [D,H]
                         const float* __restrict__ bq,    // [D]
                         const float* __restrict__ Wk,    // [D,H]
                         const float* __restrict__ bk,    // [D]
                         float* __restrict__ out)         // [B,1,S]
{
    __shared__ float attS[SS];            // 16 KB attention logits
    __shared__ float redM[WAVES], redS[WAVES];

    const int t    = threadIdx.x;
    const int b    = blockIdx.x;
    const int lane = t & 63;
    const int wv   = t >> 6;
    const int l15  = lane & 15;           // MFMA m / n index
    const int quad = lane >> 4;           // MFMA k-slice / row quadrant

    const float* encb = enc + (size_t)b * SS * HH;
    const int rowbase = wv * RPW;

    // Lane's A-source for tile i: row = rowbase + i*16 + l15, cols quad*8..+7.
    // Wave footprint per tile = 16 rows x 128 B contiguous -> fully coalesced.
    const float* src0 = encb + (size_t)(rowbase + l15) * HH + quad * 8;

    // ---- fill the register pipeline FIRST so loads fly during kn setup ----
    float4 pf[DEPTH][2];
#pragma unroll
    for (int s = 0; s < DEPTH; ++s) {
        const float* p = src0 + (size_t)s * 16 * HH;
        pf[s][0] = *(const float4*)p;
        pf[s][1] = *(const float4*)(p + 4);
    }

    // ---- B fragment: Wq[d=l15][h=quad*8+j] as bf16, resident in 4 VGPRs ----
    short8 bfrag;
    {
        const float* wp = Wq + l15 * HH + quad * 8;
        float4 w0 = *(const float4*)wp;
        float4 w1 = *(const float4*)(wp + 4);
        bfrag[0] = bf16_of(w0.x); bfrag[1] = bf16_of(w0.y);
        bfrag[2] = bf16_of(w0.z); bfrag[3] = bf16_of(w0.w);
        bfrag[4] = bf16_of(w1.x); bfrag[5] = bf16_of(w1.y);
        bfrag[6] = bf16_of(w1.z); bfrag[7] = bf16_of(w1.w);
    }
    const float bqV = bq[l15];

    // ---- kn[l15] per lane, barrier-free: lane computes its own d=l15 row of
    // Wk (vector loads, tiny + L2-hot), dec is uniform (s_loads); norm via DPP ----
    float knV;
    {
        float a = bk[l15];
        const float* wk = Wk + l15 * HH;
#pragma unroll
        for (int h = 0; h < HH; ++h) a = fmaf(wk[h], dec[b * HH + h], a);
        float ssk = red16(a * a);
        knV = a * (1.f / fmaxf(sqrtf(ssk), EPSI));
    }

    // ---- barrier-free streaming loop: rotate DEPTH pipeline slots ----
    float* attW = attS + rowbase;
    for (int g = 0; g < NGRP; ++g) {
#pragma unroll
        for (int s = 0; s < DEPTH; ++s) {
            const int i = g * DEPTH + s;
            // consume slot s (vmcnt wait is fine-grained: later slots stay in flight)
            float4 p0 = pf[s][0];
            float4 p1 = pf[s][1];
            // refill slot s with tile i+DEPTH
            if (g + 1 < NGRP) {
                const float* p = src0 + (size_t)(i + DEPTH) * 16 * HH;
                pf[s][0] = *(const float4*)p;
                pf[s][1] = *(const float4*)(p + 4);
            }
            short8 afrag;
            afrag[0] = bf16_of(p0.x); afrag[1] = bf16_of(p0.y);
            afrag[2] = bf16_of(p0.z); afrag[3] = bf16_of(p0.w);
            afrag[4] = bf16_of(p1.x); afrag[5] = bf16_of(p1.y);
            afrag[6] = bf16_of(p1.z); afrag[7] = bf16_of(p1.w);

            floatx4 acc = {0.f, 0.f, 0.f, 0.f};
            acc = __builtin_amdgcn_mfma_f32_16x16x32_bf16(afrag, bfrag, acc, 0, 0, 0);

            // acc[r] = qlin[row = i*16 + quad*4 + r][d = l15]
            float4 av; float* avp = &av.x;
#pragma unroll
            for (int r = 0; r < 4; ++r) {
                float qv = acc[r] + bqV;
                float ss = red16(qv * qv);
                float nu = red16(qv * knV);
                avp[r] = nu / fmaxf(sqrtf(ss), EPSI);
            }
            if (l15 == 0)   // 4 writer lanes/wave, contiguous 16 B each
                *(float4*)&attW[i * 16 + quad * 4] = av;
        }
    }
    __syncthreads();   // the ONLY barrier before the softmax

    // ---- block log-softmax over attS[4096] ----
    float m = -INFINITY;
#pragma unroll
    for (int i = 0; i < 16; ++i) m = fmaxf(m, attS[t + i * NT]);
#pragma unroll
    for (int off = 32; off >= 1; off >>= 1) m = fmaxf(m, __shfl_down(m, off));
    if (lane == 0) redM[wv] = m;
    __syncthreads();
    const float M = fmaxf(fmaxf(redM[0], redM[1]), fmaxf(redM[2], redM[3]));

    float s = 0.f;
#pragma unroll
    for (int i = 0; i < 16; ++i) s += __expf(attS[t + i * NT] - M);
#pragma unroll
    for (int off = 32; off >= 1; off >>= 1) s += __shfl_down(s, off);
    if (lane == 0) redS[wv] = s;
    __syncthreads();
    const float S = (redS[0] + redS[1]) + (redS[2] + redS[3]);
    const float logZ = M + __logf(S);

    // coalesced float4 output
    float4* ob4 = (float4*)(out + (size_t)b * SS);
#pragma unroll
    for (int i = 0; i < 4; ++i) {
        float4 a4 = *(const float4*)&attS[(t + i * NT) * 4];
        a4.x -= logZ; a4.y -= logZ; a4.z -= logZ; a4.w -= logZ;
        ob4[t + i * NT] = a4;
    }
}

extern "C" void kernel_launch(void* const* d_in, const int* in_sizes, int n_in,
                              void* d_out, int out_size, void* d_ws, size_t ws_size,
                              hipStream_t stream) {
    const float* dec = (const float*)d_in[0];  // [512,32]
    const float* enc = (const float*)d_in[1];  // [512,4096,32]
    const float* Wq  = (const float*)d_in[2];  // [16,32]
    const float* bq  = (const float*)d_in[3];  // [16]
    const float* Wk  = (const float*)d_in[4];  // [16,32]
    const float* bk  = (const float*)d_in[5];  // [16]
    float* out = (float*)d_out;                // [512,1,4096]

    attn_cos_logsoftmax<<<dim3(BB), dim3(NT), 0, stream>>>(dec, enc, Wq, bq, Wk, bk, out);
}